// Round 1
// baseline (395.597 us; speedup 1.0000x reference)
//
#include <hip/hip_runtime.h>
#include <hip/hip_bf16.h>

// Problem constants (match reference)
#define N_NODES  100000
#define N_EDGES  1600000
#define N_GRAPHS 2048
#define DIM      128   // IN_DIM == HIDDEN == 128
#define ELLW     64    // padded edges/node; deg ~ Poisson(16), max ~40

// ---- bf16 helpers (RNE encode, bit-shift decode) --------------------------
__device__ __forceinline__ unsigned short f2b(float f) {
    unsigned u = __float_as_uint(f);
    u += 0x7FFFu + ((u >> 16) & 1u);
    return (unsigned short)(u >> 16);
}
__device__ __forceinline__ float b2f(unsigned short h) {
    return __uint_as_float(((unsigned)h) << 16);
}
__device__ __forceinline__ float4 dec4(ushort4 h) {
    return make_float4(b2f(h.x), b2f(h.y), b2f(h.z), b2f(h.w));
}

// MFMA fragment types (gfx950, 16x16x32 bf16: 8 bf16 in / 4 fp32 acc)
typedef __attribute__((ext_vector_type(8))) short bfrag;
typedef __attribute__((ext_vector_type(4))) float ffrag;

// ===========================================================================
// Cast fp32 -> bf16 (8 elems/thread). Also: zeroes cursor[] and casts+
// transposes the 3 weights (first 49152 threads) -- one dispatch fewer.
// ===========================================================================
__global__ __launch_bounds__(256)
void cast_bf16(const float* __restrict__ in, unsigned short* __restrict__ out,
               int* __restrict__ cursor,
               const float* __restrict__ Wa, unsigned short* __restrict__ Ta,
               const float* __restrict__ Wb, unsigned short* __restrict__ Tb,
               const float* __restrict__ Wc, unsigned short* __restrict__ Tc,
               int n8)
{
    int i = blockIdx.x * 256 + threadIdx.x;
    if (i < N_NODES) cursor[i] = 0;
    if (i < 3 * DIM * DIM) {
        int which = i >> 14;              // 16384 elems per weight
        int idx   = i & (DIM * DIM - 1);
        const float* W = (which == 0) ? Wa : (which == 1) ? Wb : Wc;
        unsigned short* T = (which == 0) ? Ta : (which == 1) ? Tb : Tc;
        int k = idx >> 7, n = idx & 127;
        T[n * DIM + k] = f2b(W[idx]);
    }
    if (i >= n8) return;
    const float4* in4 = (const float4*)in;
    float4 a = in4[i * 2 + 0];
    float4 b = in4[i * 2 + 1];
    uint4 q;
    q.x = (unsigned)f2b(a.x) | ((unsigned)f2b(a.y) << 16);
    q.y = (unsigned)f2b(a.z) | ((unsigned)f2b(a.w) << 16);
    q.z = (unsigned)f2b(b.x) | ((unsigned)f2b(b.y) << 16);
    q.w = (unsigned)f2b(b.z) | ((unsigned)f2b(b.w) << 16);
    ((uint4*)out)[i] = q;
}

// ===========================================================================
// ELL fill: pos = cursor[dst]++;  ell[dst*ELLW + pos] = src
// XCD-range-partitioned (round-4 win): range r = blockIdx&7 owns dst in
// [r*12500,(r+1)*12500) -> per-range ELL window 3.2 MB < 4 MB L2.
// Also zeroes g[] (1024 blocks x 256 = exactly N_GRAPHS*DIM).
// ===========================================================================
#define FILL_RANGES 8
#define FILL_RSIZE  (N_NODES / FILL_RANGES)   // 12500 exact

__global__ __launch_bounds__(256)
void ell_fill(const int* __restrict__ src, const int* __restrict__ dst,
              int* __restrict__ cursor, int* __restrict__ ell,
              float* __restrict__ g, int E)
{
    int gid = blockIdx.x * 256 + threadIdx.x;   // grid=1024 -> covers |g|
    g[gid] = 0.f;

    const int r = blockIdx.x & (FILL_RANGES - 1);
    const int s = blockIdx.x >> 3;
    const int nslice = gridDim.x >> 3;
    const unsigned lo = (unsigned)(r * FILL_RSIZE);
    const int stride = nslice * 256 * 4;

    for (int e0 = (s * 256 + threadIdx.x) * 4; e0 < E; e0 += stride) {
        int4 d  = *(const int4*)&dst[e0];
        int4 sv = *(const int4*)&src[e0];
        if ((unsigned)(d.x - lo) < (unsigned)FILL_RSIZE) {
            int p = atomicAdd(&cursor[d.x], 1); ell[d.x * ELLW + p] = sv.x;
        }
        if ((unsigned)(d.y - lo) < (unsigned)FILL_RSIZE) {
            int p = atomicAdd(&cursor[d.y], 1); ell[d.y * ELLW + p] = sv.y;
        }
        if ((unsigned)(d.z - lo) < (unsigned)FILL_RSIZE) {
            int p = atomicAdd(&cursor[d.z], 1); ell[d.z * ELLW + p] = sv.z;
        }
        if ((unsigned)(d.w - lo) < (unsigned)FILL_RSIZE) {
            int p = atomicAdd(&cursor[d.w], 1); ell[d.w * ELLW + p] = sv.w;
        }
    }
}

// ===========================================================================
// FUSED: GIN ELL-gather (bf16, fp32 acc) directly into the MLP's LDS H tile,
// then the 3-layer MLP via MFMA 16x16x32 bf16 (W staged in LDS).
// Eliminates the 25.6 MB hb round-trip (write+read) and one dispatch, and
// drops the global dinv array (rsqrt(deg+1) kept in a 64-entry LDS array).
// Gather: 8 groups of 32 lanes, 8 sequential nodes/group (same shape as
// gcn_gather_pool, which sits at the random-read delivery plateau; round-13
// showed occupancy is NOT the limiter there, so 3 blocks/CU here is OK).
// Block = 256 thr = 4 waves; 64 rows; wave w owns 16 rows (row-parallel).
// LDS: Hb 17.4K + Ws 34.8K + dvs 0.25K = 52.5K -> 3 blocks/CU.
// A-frag: A[m=lane&15][k=quad*8+j]; B-frag from Ws[n][k];
// C/D: col=lane&15, row=quad*4+reg (verified layouts, m89/m120).
// ===========================================================================
#define MLP_ROWS 64
#define HBST     136

__global__ __launch_bounds__(256)
void mlp3_fused(const int* __restrict__ deg, const int* __restrict__ ell,
                const unsigned short* __restrict__ xb,
                const unsigned short* __restrict__ w1t, const float* __restrict__ b1,
                const unsigned short* __restrict__ w2t, const float* __restrict__ b2,
                const unsigned short* __restrict__ w3t,
                unsigned short* __restrict__ ub_out, int N)
{
    __shared__ unsigned short Hb[MLP_ROWS][HBST];
    __shared__ unsigned short Ws[DIM][HBST];
    __shared__ float dvs[MLP_ROWS];

    const int tid  = threadIdx.x;
    const int row0 = blockIdx.x * MLP_ROWS;

    // ---- gather phase: H[r] = x[node] + sum_{e<deg} x[ell[node][e]] -------
    {
        const int grp = tid >> 5;        // 0..7: rows grp*8..grp*8+7
        const int gl  = tid & 31;        // lane covers cols gl*4..gl*4+3
        const ushort4* V4 = (const ushort4*)xb;
        for (int k = 0; k < 8; ++k) {
            int r = grp * 8 + k;
            int node = row0 + r;
            if (node >= N) break;
            int dn = deg[node];
            if (gl == 0) dvs[r] = rsqrtf((float)dn + 1.0f);
            const int* row = ell + (size_t)node * ELLW;
            float4 acc = dec4(V4[(size_t)node * 32 + gl]);   // self term
            int e = 0;
            for (; e + 8 <= dn; e += 8) {
                int s0 = row[e + 0], s1 = row[e + 1], s2 = row[e + 2], s3 = row[e + 3];
                int s4 = row[e + 4], s5 = row[e + 5], s6 = row[e + 6], s7 = row[e + 7];
                float4 v0 = dec4(V4[(size_t)s0 * 32 + gl]);
                float4 v1 = dec4(V4[(size_t)s1 * 32 + gl]);
                float4 v2 = dec4(V4[(size_t)s2 * 32 + gl]);
                float4 v3 = dec4(V4[(size_t)s3 * 32 + gl]);
                float4 v4 = dec4(V4[(size_t)s4 * 32 + gl]);
                float4 v5 = dec4(V4[(size_t)s5 * 32 + gl]);
                float4 v6 = dec4(V4[(size_t)s6 * 32 + gl]);
                float4 v7 = dec4(V4[(size_t)s7 * 32 + gl]);
                acc.x += (v0.x + v1.x + v2.x + v3.x) + (v4.x + v5.x + v6.x + v7.x);
                acc.y += (v0.y + v1.y + v2.y + v3.y) + (v4.y + v5.y + v6.y + v7.y);
                acc.z += (v0.z + v1.z + v2.z + v3.z) + (v4.z + v5.z + v6.z + v7.z);
                acc.w += (v0.w + v1.w + v2.w + v3.w) + (v4.w + v5.w + v6.w + v7.w);
            }
            for (; e + 4 <= dn; e += 4) {
                int s0 = row[e + 0], s1 = row[e + 1], s2 = row[e + 2], s3 = row[e + 3];
                float4 v0 = dec4(V4[(size_t)s0 * 32 + gl]);
                float4 v1 = dec4(V4[(size_t)s1 * 32 + gl]);
                float4 v2 = dec4(V4[(size_t)s2 * 32 + gl]);
                float4 v3 = dec4(V4[(size_t)s3 * 32 + gl]);
                acc.x += v0.x + v1.x + v2.x + v3.x;
                acc.y += v0.y + v1.y + v2.y + v3.y;
                acc.z += v0.z + v1.z + v2.z + v3.z;
                acc.w += v0.w + v1.w + v2.w + v3.w;
            }
            for (; e < dn; ++e) {
                int s = row[e];
                float4 v = dec4(V4[(size_t)s * 32 + gl]);
                acc.x += v.x; acc.y += v.y; acc.z += v.z; acc.w += v.w;
            }
            ushort4 o;
            o.x = f2b(acc.x); o.y = f2b(acc.y); o.z = f2b(acc.z); o.w = f2b(acc.w);
            *(ushort4*)&Hb[r][gl * 4] = o;   // row base 272 B, 8B-aligned steps
        }
    }
    // gather writes (Hb, dvs) fenced by the layer-0 barriers below

    const int wave = tid >> 6;        // 0..3
    const int lane = tid & 63;
    const int m0 = wave * 16;
    const int qa = lane >> 4;         // quad 0..3
    const int la = lane & 15;

    for (int layer = 0; layer < 3; ++layer) {
        const unsigned short* __restrict__ Wt =
            (layer == 0) ? w1t : (layer == 1) ? w2t : w3t;

        // ---- stage Wt[128][128] -> Ws: 2048 uint4, 8/thread (L2-hot) ----
        __syncthreads();   // prior-layer Ws reads (and gather phase) done
#pragma unroll
        for (int l = 0; l < 8; ++l) {
            int f  = tid + l * 256;   // 0..2047
            int r  = f >> 4;          // 0..127
            int c8 = (f & 15) << 3;
            *(uint4*)&Ws[r][c8] = *(const uint4*)&Wt[(size_t)r * DIM + c8];
        }
        __syncthreads();

        // A fragments for this wave's 16 rows, all K (4 chunks of 32)
        bfrag afr[4];
#pragma unroll
        for (int kc = 0; kc < 4; ++kc)
            afr[kc] = *(const bfrag*)&Hb[m0 + la][kc * 32 + qa * 8];

        if (layer < 2) {
            const float* bias = (layer == 0) ? b1 : b2;
#pragma unroll
            for (int nt = 0; nt < 8; ++nt) {
                const int n0 = nt * 16;
                ffrag acc = {0.f, 0.f, 0.f, 0.f};
#pragma unroll
                for (int kc = 0; kc < 4; ++kc) {
                    bfrag bfr = *(const bfrag*)&Ws[n0 + la][kc * 32 + qa * 8];
                    acc = __builtin_amdgcn_mfma_f32_16x16x32_bf16(afr[kc], bfr, acc, 0, 0, 0);
                }
                float bn = bias[n0 + la];
#pragma unroll
                for (int r = 0; r < 4; ++r) {
                    float v = fmaxf(acc[r] + bn, 0.f);
                    Hb[m0 + qa * 4 + r][n0 + la] = f2b(v);
                }
            }
            // wave-private rows: program order suffices before next layer
        } else {
            float dv[4];
#pragma unroll
            for (int r = 0; r < 4; ++r)
                dv[r] = dvs[m0 + qa * 4 + r];   // garbage for rows >= N: store guarded
#pragma unroll
            for (int nt = 0; nt < 8; ++nt) {
                const int n0 = nt * 16;
                ffrag acc = {0.f, 0.f, 0.f, 0.f};
#pragma unroll
                for (int kc = 0; kc < 4; ++kc) {
                    bfrag bfr = *(const bfrag*)&Ws[n0 + la][kc * 32 + qa * 8];
                    acc = __builtin_amdgcn_mfma_f32_16x16x32_bf16(afr[kc], bfr, acc, 0, 0, 0);
                }
#pragma unroll
                for (int r = 0; r < 4; ++r) {
                    int gr = row0 + m0 + qa * 4 + r;
                    if (gr < N)
                        ub_out[(size_t)gr * DIM + n0 + la] = f2b(dv[r] * acc[r]);
                }
            }
        }
    }
}

// ===========================================================================
// Fused GCN gather (bf16 u, ELL) + finalize + global_add_pool.
// P2_NODES=64 (8 sequential nodes per 32-lane group): round-13 showed 32
// doubles pool-atomic WRITE (28.6->53 MB) and regresses 82->97 us; run-length
// batching needs the longer per-group node run. Occupancy is NOT the pool's
// limiter (random-read delivery plateau is).
// dinv computed locally from deg (same rsqrtf as producer -> bit-identical).
// ===========================================================================
#define P2_NODES 64
__global__ __launch_bounds__(256)
void gcn_gather_pool(const int* __restrict__ deg, const int* __restrict__ ell,
                     const unsigned short* __restrict__ ub,
                     const float* __restrict__ bias, const int* __restrict__ batch,
                     float* __restrict__ g, int N)
{
    const int grp  = threadIdx.x >> 5;
    const int lane = threadIdx.x & 31;
    const int n0   = blockIdx.x * P2_NODES + grp * 8;
    const ushort4* V4 = (const ushort4*)ub;

    float4 bj;
    bj.x = bias[lane * 4 + 0];
    bj.y = bias[lane * 4 + 1];
    bj.z = bias[lane * 4 + 2];
    bj.w = bias[lane * 4 + 3];

    float4 lsum = make_float4(0.f, 0.f, 0.f, 0.f);
    int prev = -1;

    for (int k = 0; k < 8; ++k) {
        int node = n0 + k;
        if (node >= N) break;
        int dn = deg[node];
        const int* row = ell + node * ELLW;
        float4 acc = dec4(V4[(size_t)node * 32 + lane]);   // self term u_i
        int e = 0;
        for (; e + 8 <= dn; e += 8) {
            int s0 = row[e + 0], s1 = row[e + 1], s2 = row[e + 2], s3 = row[e + 3];
            int s4 = row[e + 4], s5 = row[e + 5], s6 = row[e + 6], s7 = row[e + 7];
            float4 v0 = dec4(V4[(size_t)s0 * 32 + lane]);
            float4 v1 = dec4(V4[(size_t)s1 * 32 + lane]);
            float4 v2 = dec4(V4[(size_t)s2 * 32 + lane]);
            float4 v3 = dec4(V4[(size_t)s3 * 32 + lane]);
            float4 v4 = dec4(V4[(size_t)s4 * 32 + lane]);
            float4 v5 = dec4(V4[(size_t)s5 * 32 + lane]);
            float4 v6 = dec4(V4[(size_t)s6 * 32 + lane]);
            float4 v7 = dec4(V4[(size_t)s7 * 32 + lane]);
            acc.x += (v0.x + v1.x + v2.x + v3.x) + (v4.x + v5.x + v6.x + v7.x);
            acc.y += (v0.y + v1.y + v2.y + v3.y) + (v4.y + v5.y + v6.y + v7.y);
            acc.z += (v0.z + v1.z + v2.z + v3.z) + (v4.z + v5.z + v6.z + v7.z);
            acc.w += (v0.w + v1.w + v2.w + v3.w) + (v4.w + v5.w + v6.w + v7.w);
        }
        for (; e + 4 <= dn; e += 4) {
            int s0 = row[e + 0], s1 = row[e + 1], s2 = row[e + 2], s3 = row[e + 3];
            float4 v0 = dec4(V4[(size_t)s0 * 32 + lane]);
            float4 v1 = dec4(V4[(size_t)s1 * 32 + lane]);
            float4 v2 = dec4(V4[(size_t)s2 * 32 + lane]);
            float4 v3 = dec4(V4[(size_t)s3 * 32 + lane]);
            acc.x += v0.x + v1.x + v2.x + v3.x;
            acc.y += v0.y + v1.y + v2.y + v3.y;
            acc.z += v0.z + v1.z + v2.z + v3.z;
            acc.w += v0.w + v1.w + v2.w + v3.w;
        }
        for (; e < dn; ++e) {
            int s = row[e];
            float4 v = dec4(V4[(size_t)s * 32 + lane]);
            acc.x += v.x; acc.y += v.y; acc.z += v.z; acc.w += v.w;
        }
        float di = rsqrtf((float)dn + 1.0f);
        float4 h;
        h.x = fmaxf(fmaf(di, acc.x, bj.x), 0.f);
        h.y = fmaxf(fmaf(di, acc.y, bj.y), 0.f);
        h.z = fmaxf(fmaf(di, acc.z, bj.z), 0.f);
        h.w = fmaxf(fmaf(di, acc.w, bj.w), 0.f);

        int b = batch[node];
        if (b != prev) {
            if (prev >= 0) {
                float* gp = &g[(size_t)prev * DIM + lane * 4];
                atomicAdd(gp + 0, lsum.x);
                atomicAdd(gp + 1, lsum.y);
                atomicAdd(gp + 2, lsum.z);
                atomicAdd(gp + 3, lsum.w);
            }
            lsum = make_float4(0.f, 0.f, 0.f, 0.f);
            prev = b;
        }
        lsum.x += h.x; lsum.y += h.y; lsum.z += h.z; lsum.w += h.w;
    }
    if (prev >= 0) {
        float* gp = &g[(size_t)prev * DIM + lane * 4];
        atomicAdd(gp + 0, lsum.x);
        atomicAdd(gp + 1, lsum.y);
        atomicAdd(gp + 2, lsum.z);
        atomicAdd(gp + 3, lsum.w);
    }
}

// ===========================================================================
// Head: out[gid] = relu(g[gid] @ lin1_w + b1) @ lin2_w + b2
// ===========================================================================
__global__ __launch_bounds__(128)
void head_kernel(const float* __restrict__ g, const float* __restrict__ w1,
                 const float* __restrict__ b1, const float* __restrict__ w2,
                 const float* __restrict__ b2, float* __restrict__ out)
{
    __shared__ float gs[DIM];
    __shared__ float red[6];
    int gid = blockIdx.x;
    int t = threadIdx.x;

    gs[t] = g[(size_t)gid * DIM + t];
    __syncthreads();

    float acc = b1[t];
#pragma unroll
    for (int k = 0; k < DIM; ++k) acc = fmaf(gs[k], w1[k * DIM + t], acc);
    float h = fmaxf(acc, 0.f);

    float c0 = h * w2[t * 3 + 0];
    float c1 = h * w2[t * 3 + 1];
    float c2 = h * w2[t * 3 + 2];
#pragma unroll
    for (int off = 32; off >= 1; off >>= 1) {
        c0 += __shfl_down(c0, off);
        c1 += __shfl_down(c1, off);
        c2 += __shfl_down(c2, off);
    }
    int wave = t >> 6;
    if ((t & 63) == 0) {
        red[wave * 3 + 0] = c0;
        red[wave * 3 + 1] = c1;
        red[wave * 3 + 2] = c2;
    }
    __syncthreads();
    if (t == 0) {
        out[(size_t)gid * 3 + 0] = red[0] + red[3] + b2[0];
        out[(size_t)gid * 3 + 1] = red[1] + red[4] + b2[1];
        out[(size_t)gid * 3 + 2] = red[2] + red[5] + b2[2];
    }
}

// ===========================================================================
extern "C" void kernel_launch(void* const* d_in, const int* in_sizes, int n_in,
                              void* d_out, int out_size, void* d_ws, size_t ws_size,
                              hipStream_t stream)
{
    const float* x       = (const float*)d_in[0];
    const int*   eidx    = (const int*)d_in[1];
    const int*   batch   = (const int*)d_in[2];
    const float* gin_w1  = (const float*)d_in[3];
    const float* gin_b1  = (const float*)d_in[4];
    const float* gin_w2  = (const float*)d_in[5];
    const float* gin_b2  = (const float*)d_in[6];
    const float* gcn_w   = (const float*)d_in[7];
    const float* gcn_b   = (const float*)d_in[8];
    const float* lin1_w  = (const float*)d_in[9];
    const float* lin1_b  = (const float*)d_in[10];
    const float* lin2_w  = (const float*)d_in[11];
    const float* lin2_b  = (const float*)d_in[12];

    const int* src = eidx;
    const int* dst = eidx + N_EDGES;

    // workspace carve (256B aligned); total ~78 MB
    const size_t NBH = (size_t)N_NODES * DIM * sizeof(unsigned short); // 25.6 MB
    const size_t WTB = (size_t)DIM * DIM * sizeof(unsigned short);     // 32 KB
    char* base = (char*)d_ws;
    size_t off = 0;
    auto carve = [&](size_t bytes) {
        char* p = base + off;
        off = (off + bytes + 255) & ~(size_t)255;
        return p;
    };
    unsigned short* xb  = (unsigned short*)carve(NBH);  // x in bf16
    unsigned short* ub  = (unsigned short*)carve(NBH);  // u in bf16
    unsigned short* w1t = (unsigned short*)carve(WTB);  // gin_w1^T bf16
    unsigned short* w2t = (unsigned short*)carve(WTB);
    unsigned short* w3t = (unsigned short*)carve(WTB);
    int*   cursor = (int*)  carve(N_NODES * sizeof(int));              // -> deg
    int*   ell    = (int*)  carve((size_t)N_NODES * ELLW * sizeof(int)); // 25.6MB
    float* g      = (float*)carve((size_t)N_GRAPHS * DIM * sizeof(float));

    const int mgrid = (N_NODES + MLP_ROWS - 1) / MLP_ROWS;
    const int pgrid = (N_NODES + P2_NODES - 1) / P2_NODES;

    // ---- casts + weight transpose + cursor zeroing (one dispatch) ----
    cast_bf16<<<(N_NODES * DIM / 8 + 255) / 256, 256, 0, stream>>>(
        x, xb, cursor, gin_w1, w1t, gin_w2, w2t, gcn_w, w3t,
        N_NODES * DIM / 8);

    // ---- ELL build (also zeroes g); cursor ends as degree ----
    ell_fill<<<FILL_RANGES * 128, 256, 0, stream>>>(src, dst, cursor, ell,
                                                    g, N_EDGES);

    // ---- fused GIN gather + 3-layer MLP via MFMA -> u (bf16) ----
    mlp3_fused<<<mgrid, 256, 0, stream>>>(cursor, ell, xb, w1t, gin_b1,
                                          w2t, gin_b2, w3t, ub, N_NODES);

    // ---- fused GCN gather (bf16) + finalize + pool -> g ----
    gcn_gather_pool<<<pgrid, 256, 0, stream>>>(cursor, ell, ub, gcn_b,
                                               batch, g, N_NODES);

    // ---- head ----
    head_kernel<<<N_GRAPHS, 128, 0, stream>>>(
        g, lin1_w, lin1_b, lin2_w, lin2_b, (float*)d_out);
}